// Round 1
// baseline (1455.449 us; speedup 1.0000x reference)
//
#include <hip/hip_runtime.h>

#define NB 64
#define NT 4096
#define DD 256
#define CH 64
#define KC (NT/CH)   // 64 chunks per batch

// D = A @ B for 16x16 matrices in LDS; 256 threads, thread (i,j) owns one elem.
// Callers guarantee inputs are barrier-visible before entry.
__device__ __forceinline__ void mm16(float* D, const float* A, const float* B,
                                     int i, int j, int tid) {
    float acc = 0.f;
#pragma unroll
    for (int k = 0; k < 16; ++k) acc = fmaf(A[i*16+k], B[k*16+j], acc);
    __syncthreads();          // all reads of A/B (and old D) done
    D[tid] = acc;
    __syncthreads();          // D visible
}

// Kernel 1: per-chunk local scan.  L[t] = prod_{s=chunk_start (or 1)}^{t} M_s
// written into the A-output region (chunk tail slot == chunk total).
__global__ __launch_bounds__(256) void k1_chunk(const float* __restrict__ Z,
                                                const float* __restrict__ A1,
                                                const float* __restrict__ A2,
                                                float* __restrict__ Aout)
{
    __shared__ float Gs[DD], G2[DD], G3[DD], G4[DD], Ea[DD], Eb[DD], La[DD], Lb[DD];
    __shared__ float red[16];
    __shared__ float nrm_s[2];

    const int tid = threadIdx.x;
    const int i = tid >> 4, j = tid & 15;
    const int b = blockIdx.x / KC;
    const int kchunk = blockIdx.x % KC;
    const int t0 = kchunk * CH;

    const float s1 = A1[i*16+j] - A1[j*16+i];
    const float s2 = A2[i*16+j] - A2[j*16+i];
    const float idel = (i == j) ? 1.f : 0.f;

    // ||S1||_1 and ||S2||_1 (max column abs-sum), once per block.
    Gs[tid] = fabsf(s1);
    __syncthreads();
    if (tid < 16) { float s = 0.f; for (int r = 0; r < 16; ++r) s += Gs[r*16+tid]; red[tid] = s; }
    __syncthreads();
    if (tid == 0) { float m = 0.f; for (int c = 0; c < 16; ++c) m = fmaxf(m, red[c]); nrm_s[0] = m; }
    __syncthreads();
    Gs[tid] = fabsf(s2);
    __syncthreads();
    if (tid < 16) { float s = 0.f; for (int r = 0; r < 16; ++r) s += Gs[r*16+tid]; red[tid] = s; }
    __syncthreads();
    if (tid == 0) { float m = 0.f; for (int c = 0; c < 16; ++c) m = fmaxf(m, red[c]); nrm_s[1] = m; }
    __syncthreads();
    const float n1 = nrm_s[0], n2 = nrm_s[1];

    float* L  = La;
    float* Ln = Lb;
    L[tid] = idel;
    __syncthreads();

    const float c3_ = 1.f/6.f,    c4_ = 1.f/24.f,   c5_ = 1.f/120.f,
                c6_ = 1.f/720.f,  c7_ = 1.f/5040.f, c8_ = 1.f/40320.f;

    for (int t = t0; t < t0 + CH; ++t) {
        if (t == 0) {                      // A[b,0] = I, M[:,0] unused
            Aout[(size_t)(b*NT + 0)*DD + tid] = idel;
            continue;
        }
        const float z1 = Z[(size_t)(b*NT + t)*2 + 0];
        const float z2 = Z[(size_t)(b*NT + t)*2 + 1];
        const float nrm = fabsf(z1)*n1 + fabsf(z2)*n2;   // >= ||G||_1
        int s = 0;
        if (nrm > 0.5f) {                  // scale so ||G/2^s||_1 <= 0.5
            s = (int)ceilf(log2f(nrm * 2.0f));
            if (s < 0) s = 0;
        }
        const float scl = exp2f(-(float)s);
        Gs[tid] = (z1*s1 + z2*s2) * scl;
        __syncthreads();

        // Paterson-Stockmeyer degree-8 Taylor: 4 matmuls
        mm16(G2, Gs, Gs, i, j, tid);
        mm16(G3, G2, Gs, i, j, tid);
        mm16(G4, G2, G2, i, j, tid);
        Ea[tid] = c5_*Gs[tid] + c6_*G2[tid] + c7_*G3[tid] + c8_*G4[tid];  // U
        __syncthreads();
        mm16(Eb, G4, Ea, i, j, tid);                                      // G4*U
        Ea[tid] = idel + Gs[tid] + 0.5f*G2[tid] + c3_*G3[tid] + c4_*G4[tid] + Eb[tid];
        __syncthreads();

        // s squarings (s is block-uniform -> barriers are safe)
        float* E  = Ea;
        float* Eo = Eb;
        for (int q = 0; q < s; ++q) {
            mm16(Eo, E, E, i, j, tid);
            float* tp = E; E = Eo; Eo = tp;
        }

        // L = L @ M, write local prefix to A region
        float acc = 0.f;
#pragma unroll
        for (int k = 0; k < 16; ++k) acc = fmaf(L[i*16+k], E[k*16+j], acc);
        __syncthreads();
        Ln[tid] = acc;
        Aout[(size_t)(b*NT + t)*DD + tid] = acc;
        __syncthreads();
        float* tp = L; L = Ln; Ln = tp;
    }
}

// Kernel 2: per-batch exclusive scan over chunk totals.
// Carry_k = prod_{c<k} ChunkTotal_c, stored into the B_inv region at slot t=k*CH
// (dead space until kernel 3 overwrites it).
__global__ __launch_bounds__(256) void k2_carry(const float* __restrict__ Aout,
                                                float* __restrict__ Binv)
{
    __shared__ float Cy[DD], Lt[DD];
    const int tid = threadIdx.x;
    const int i = tid >> 4, j = tid & 15;
    const int b = blockIdx.x;
    const float idel = (i == j) ? 1.f : 0.f;
    Cy[tid] = idel;
    Binv[(size_t)(b*NT + 0)*DD + tid] = idel;
    __syncthreads();
    for (int k = 1; k < KC; ++k) {
        Lt[tid] = Aout[(size_t)(b*NT + k*CH - 1)*DD + tid];  // chunk total of k-1
        __syncthreads();
        float acc = 0.f;
#pragma unroll
        for (int m = 0; m < 16; ++m) acc = fmaf(Cy[i*16+m], Lt[m*16+j], acc);
        __syncthreads();
        Cy[tid] = acc;
        Binv[(size_t)(b*NT + k*CH)*DD + tid] = acc;
        __syncthreads();
    }
}

// Kernel 3: A[t] = Carry_chunk @ L[t]; B_inv[t] = A[t]^T (A orthogonal).
__global__ __launch_bounds__(256) void k3_apply(float* __restrict__ Aout,
                                                float* __restrict__ Binv)
{
    __shared__ float Cy[DD], Lt[DD];
    const int tid = threadIdx.x;
    const int i = tid >> 4, j = tid & 15;
    const int b = blockIdx.x / KC;
    const int kchunk = blockIdx.x % KC;
    const int t0 = kchunk * CH;
    Cy[tid] = Binv[(size_t)(b*NT + t0)*DD + tid];   // this chunk's carry
    __syncthreads();
    for (int t = t0; t < t0 + CH; ++t) {
        Lt[tid] = Aout[(size_t)(b*NT + t)*DD + tid];
        __syncthreads();
        float acc = 0.f;
#pragma unroll
        for (int m = 0; m < 16; ++m) acc = fmaf(Cy[i*16+m], Lt[m*16+j], acc);
        Aout[(size_t)(b*NT + t)*DD + tid] = acc;          // final A
        Binv[(size_t)(b*NT + t)*DD + j*16 + i] = acc;     // A^T
        __syncthreads();
    }
}

extern "C" void kernel_launch(void* const* d_in, const int* in_sizes, int n_in,
                              void* d_out, int out_size, void* d_ws, size_t ws_size,
                              hipStream_t stream) {
    const float* Z  = (const float*)d_in[0];   // [64, 4096, 2]
    const float* A1 = (const float*)d_in[1];   // [16, 16]
    const float* A2 = (const float*)d_in[2];   // [16, 16]
    float* Aout = (float*)d_out;                         // [64,4096,16,16]
    float* Binv = Aout + (size_t)NB * NT * DD;           // [64,4096,16,16]

    k1_chunk<<<NB * KC, 256, 0, stream>>>(Z, A1, A2, Aout);
    k2_carry<<<NB, 256, 0, stream>>>(Aout, Binv);
    k3_apply<<<NB * KC, 256, 0, stream>>>(Aout, Binv);
}

// Round 2
// 678.546 us; speedup vs baseline: 2.1450x; 2.1450x over previous
//
#include <hip/hip_runtime.h>

#define NB 64
#define NT 4096
#define CH 32
#define KC (NT/CH)      // 128 chunks per batch
#define GPB 16          // chains (16-lane groups) per 256-thread block
#define LGS 776         // LDS floats per group: 3 bufs * 256 + 8 pad (slot shift 2/group)
#define BX 0
#define BY 256
#define BZ 512

// Wave-synchronous LDS fence: drain DS queue + compiler memory barrier.
#define WSYNC() asm volatile("s_waitcnt lgkmcnt(0)" ::: "memory")

// acc[rr*4+cc] (+)= sum_k A[4tr+rr][k] * B[k][4tc+cc], group-local 16x16 mm.
// LDS layout: element (row, col) granule gc=col>>2 stored at granule (gc ^ (row>>2)).
#define MM_FMA(A_, B0_, B1_, B2_, B3_, base) \
  acc[base+0] = fmaf(A_.w, B3_.x, fmaf(A_.z, B2_.x, fmaf(A_.y, B1_.x, fmaf(A_.x, B0_.x, acc[base+0])))); \
  acc[base+1] = fmaf(A_.w, B3_.y, fmaf(A_.z, B2_.y, fmaf(A_.y, B1_.y, fmaf(A_.x, B0_.y, acc[base+1])))); \
  acc[base+2] = fmaf(A_.w, B3_.z, fmaf(A_.z, B2_.z, fmaf(A_.y, B1_.z, fmaf(A_.x, B0_.z, acc[base+2])))); \
  acc[base+3] = fmaf(A_.w, B3_.w, fmaf(A_.z, B2_.w, fmaf(A_.y, B1_.w, fmaf(A_.x, B0_.w, acc[base+3]))));

template<bool CLR>
__device__ __forceinline__ void mmg(float acc[16], const float* sb, int offA, int offB,
                                    const int xA[4], const int xB[4], int tr64) {
  if (CLR) {
#pragma unroll
    for (int e = 0; e < 16; ++e) acc[e] = 0.f;
  }
#pragma unroll
  for (int kk = 0; kk < 4; ++kk) {
    const float* pa = sb + offA + tr64 + xA[kk];
    const float* pb = sb + offB + kk*64 + xB[kk];
    float4 a0 = *(const float4*)(pa +  0);
    float4 a1 = *(const float4*)(pa + 16);
    float4 a2 = *(const float4*)(pa + 32);
    float4 a3 = *(const float4*)(pa + 48);
    float4 b0 = *(const float4*)(pb +  0);
    float4 b1 = *(const float4*)(pb + 16);
    float4 b2 = *(const float4*)(pb + 32);
    float4 b3 = *(const float4*)(pb + 48);
    MM_FMA(a0, b0, b1, b2, b3, 0)
    MM_FMA(a1, b0, b1, b2, b3, 4)
    MM_FMA(a2, b0, b1, b2, b3, 8)
    MM_FMA(a3, b0, b1, b2, b3, 12)
  }
}

__device__ __forceinline__ void st4(float* sb, int offD, const float v[16], int tr64, int xD) {
  float* p = sb + offD + tr64 + xD;
#pragma unroll
  for (int rr = 0; rr < 4; ++rr)
    *(float4*)(p + rr*16) = make_float4(v[rr*4+0], v[rr*4+1], v[rr*4+2], v[rr*4+3]);
}

// k0: n1 = ||S1||_1, n2 = ||S2||_1 into ws[0..1].
__global__ __launch_bounds__(64) void k0_norms(const float* __restrict__ A1,
                                               const float* __restrict__ A2,
                                               float* __restrict__ ws) {
  __shared__ float cs[32];
  int tid = threadIdx.x;
  if (tid < 32) {
    const float* A = (tid < 16) ? A1 : A2;
    int c = tid & 15;
    float ssum = 0.f;
    for (int r = 0; r < 16; ++r) ssum += fabsf(A[r*16+c] - A[c*16+r]);
    cs[tid] = ssum;
  }
  __syncthreads();
  if (tid == 0) { float m = 0.f; for (int c = 0; c < 16; ++c) m = fmaxf(m, cs[c]);    ws[0] = m; }
  if (tid == 1) { float m = 0.f; for (int c = 0; c < 16; ++c) m = fmaxf(m, cs[16+c]); ws[1] = m; }
}

// k1: per-chunk local scan, one chain per 16-lane group, zero barriers.
__global__ __launch_bounds__(256, 2) void k1_chunk(const float* __restrict__ Z,
                                                   const float* __restrict__ A1,
                                                   const float* __restrict__ A2,
                                                   const float* __restrict__ ws,
                                                   float* __restrict__ Aout)
{
  __shared__ __align__(16) float lds[GPB * LGS];
  const int tid = threadIdx.x;
  const int g   = tid >> 4;          // group (chain) within block
  const int u   = tid & 15;          // lane within group
  const int tr  = u >> 2;            // tile row 0..3 (rows 4tr..4tr+3)
  const int tc  = u & 3;             // tile col 0..3
  const int gw  = (tid & 63) >> 4;   // group within wave
  const int tr64 = tr * 64;

  float* sb = lds + g * LGS;
  const int xA[4] = { ((0^tr)<<2), ((1^tr)<<2), ((2^tr)<<2), ((3^tr)<<2) };
  const int xB[4] = { ((tc^0)<<2), ((tc^1)<<2), ((tc^2)<<2), ((tc^3)<<2) };
  const int xD    = ((tc^tr)<<2);

  const int cid    = blockIdx.x * GPB + g;
  const int b      = cid >> 7;       // / KC
  const int kchunk = cid & (KC-1);
  const int t0     = kchunk * CH;

  const float n1 = ws[0], n2 = ws[1];
  const float trtc = (tr == tc) ? 1.f : 0.f;

  float s1t[16], s2t[16], idt[16];
#pragma unroll
  for (int rr = 0; rr < 4; ++rr)
#pragma unroll
    for (int cc = 0; cc < 4; ++cc) {
      int r_ = 4*tr + rr, c_ = 4*tc + cc;
      s1t[rr*4+cc] = A1[r_*16 + c_] - A1[c_*16 + r_];
      s2t[rr*4+cc] = A2[r_*16 + c_] - A2[c_*16 + r_];
      idt[rr*4+cc] = (rr == cc) ? trtc : 0.f;
    }

  // z staging: lane u holds z-pairs for tt=u and tt=u+16.
  float2 za = *(const float2*)&Z[(size_t)(b*NT + t0 + u      ) * 2];
  float2 zb = *(const float2*)&Z[(size_t)(b*NT + t0 + 16 + u ) * 2];

  float lt[16], acc[16], gt[16], g2t[16], g3t[16], g4t[16];
#pragma unroll
  for (int e = 0; e < 16; ++e) lt[e] = idt[e];

  const float C3 = 1.f/6.f,   C4 = 1.f/24.f,   C5 = 1.f/120.f,
              C6 = 1.f/720.f, C7 = 1.f/5040.f, C8 = 1.f/40320.f;

  for (int tt = 0; tt < CH; ++tt) {
    const int t = t0 + tt;
    const size_t obase = (size_t)(b*NT + t) * 256 + (size_t)tr64 + 4*tc;
    if (kchunk == 0 && tt == 0) {        // A[b,0] = I; M[:,0] unused
#pragma unroll
      for (int rr = 0; rr < 4; ++rr)
        *(float4*)&Aout[obase + rr*16] = make_float4(idt[rr*4+0], idt[rr*4+1], idt[rr*4+2], idt[rr*4+3]);
      continue;
    }
    const int src = (gw << 4) + (tt & 15);
    float z1 = (tt < 16) ? __shfl(za.x, src) : __shfl(zb.x, src);
    float z2 = (tt < 16) ? __shfl(za.y, src) : __shfl(zb.y, src);

    const float nrm = fabsf(z1)*n1 + fabsf(z2)*n2;    // >= ||G||_2
    int s = 0;
    if (nrm > 0.75f) { s = (int)ceilf(log2f(nrm * (1.f/0.75f))); if (s < 0) s = 0; }
    const float scl = exp2f(-(float)s);
    z1 *= scl; z2 *= scl;

#pragma unroll
    for (int e = 0; e < 16; ++e) gt[e] = z1*s1t[e] + z2*s2t[e];
    st4(sb, BX, gt, tr64, xD);  WSYNC();

    mmg<true>(acc, sb, BX, BX, xA, xB, tr64);          // G2
#pragma unroll
    for (int e = 0; e < 16; ++e) g2t[e] = acc[e];
    st4(sb, BY, g2t, tr64, xD); WSYNC();

    mmg<true>(g3t, sb, BY, BX, xA, xB, tr64);          // G3 = G2*G
    mmg<true>(g4t, sb, BY, BY, xA, xB, tr64);          // G4 = G2*G2
    st4(sb, BX, g4t, tr64, xD);                        // X := G4 (G dead)

#pragma unroll
    for (int e = 0; e < 16; ++e) acc[e] = C5*gt[e] + C6*g2t[e] + C7*g3t[e] + C8*g4t[e];  // U
    st4(sb, BZ, acc, tr64, xD); WSYNC();

#pragma unroll
    for (int e = 0; e < 16; ++e)
      acc[e] = idt[e] + gt[e] + 0.5f*g2t[e] + C3*g3t[e] + C4*g4t[e];                     // P1
    mmg<false>(acc, sb, BX, BZ, xA, xB, tr64);         // E = P1 + G4*U
    st4(sb, BY, acc, tr64, xD); WSYNC();

    int cur = BY, oth = BX;
    for (int q = 0; q < s; ++q) {                      // s squarings (uniform per group)
      mmg<true>(acc, sb, cur, cur, xA, xB, tr64);
      st4(sb, oth, acc, tr64, xD); WSYNC();
      int tmp = cur; cur = oth; oth = tmp;
    }

    st4(sb, oth, lt, tr64, xD); WSYNC();               // L into dead buffer
    mmg<true>(acc, sb, oth, cur, xA, xB, tr64);        // Lnew = L @ E
#pragma unroll
    for (int e = 0; e < 16; ++e) lt[e] = acc[e];

#pragma unroll
    for (int rr = 0; rr < 4; ++rr)
      *(float4*)&Aout[obase + rr*16] = make_float4(lt[rr*4+0], lt[rr*4+1], lt[rr*4+2], lt[rr*4+3]);
  }
}

// k2: per-batch exclusive scan over chunk totals -> carries at Binv[b, k*CH].
__global__ __launch_bounds__(256) void k2_carry(const float* __restrict__ Aout,
                                                float* __restrict__ Binv)
{
  __shared__ float Cy[256], Lt[256];
  const int tid = threadIdx.x;
  const int i = tid >> 4, j = tid & 15;
  const int b = blockIdx.x;
  const float idel = (i == j) ? 1.f : 0.f;
  Cy[tid] = idel;
  Binv[(size_t)(b*NT) * 256 + tid] = idel;
  __syncthreads();
  for (int k = 1; k < KC; ++k) {
    Lt[tid] = Aout[(size_t)(b*NT + k*CH - 1) * 256 + tid];
    __syncthreads();
    float a2 = 0.f;
#pragma unroll
    for (int m = 0; m < 16; ++m) a2 = fmaf(Cy[i*16+m], Lt[m*16+j], a2);
    __syncthreads();
    Cy[tid] = a2;
    Binv[(size_t)(b*NT + k*CH) * 256 + tid] = a2;
    __syncthreads();
  }
}

// k3: A[t] = Carry @ L[t]; B_inv[t] = A[t]^T (A orthogonal), transposed via LDS.
__global__ __launch_bounds__(256) void k3_apply(float* __restrict__ Aout,
                                                float* __restrict__ Binv)
{
  __shared__ float Cy[256], Lt[256], Tr[16*17];
  const int tid = threadIdx.x;
  const int i = tid >> 4, j = tid & 15;
  const int b = blockIdx.x / KC;
  const int kchunk = blockIdx.x % KC;
  const int t0 = kchunk * CH;
  Cy[tid] = Binv[(size_t)(b*NT + t0) * 256 + tid];
  __syncthreads();
  for (int t = t0; t < t0 + CH; ++t) {
    Lt[tid] = Aout[(size_t)(b*NT + t) * 256 + tid];
    __syncthreads();
    float a2 = 0.f;
#pragma unroll
    for (int m = 0; m < 16; ++m) a2 = fmaf(Cy[i*16+m], Lt[m*16+j], a2);
    Aout[(size_t)(b*NT + t) * 256 + tid] = a2;
    Tr[i*17 + j] = a2;
    __syncthreads();
    Binv[(size_t)(b*NT + t) * 256 + tid] = Tr[j*17 + i];
    __syncthreads();
  }
}

extern "C" void kernel_launch(void* const* d_in, const int* in_sizes, int n_in,
                              void* d_out, int out_size, void* d_ws, size_t ws_size,
                              hipStream_t stream) {
  const float* Z  = (const float*)d_in[0];   // [64, 4096, 2]
  const float* A1 = (const float*)d_in[1];   // [16, 16]
  const float* A2 = (const float*)d_in[2];   // [16, 16]
  float* ws   = (float*)d_ws;
  float* Aout = (float*)d_out;                         // [64,4096,16,16]
  float* Binv = Aout + (size_t)NB * NT * 256;          // [64,4096,16,16]

  k0_norms<<<1, 64, 0, stream>>>(A1, A2, ws);
  k1_chunk<<<NB * KC / GPB, 256, 0, stream>>>(Z, A1, A2, ws, Aout);
  k2_carry<<<NB, 256, 0, stream>>>(Aout, Binv);
  k3_apply<<<NB * KC, 256, 0, stream>>>(Aout, Binv);
}